// Round 13
// baseline (40.695 us; speedup 1.0000x reference)
//
#include <hip/hip_runtime.h>
#include <hip/hip_bf16.h>

static constexpr int Qq = 64, Nn = 4096, Kk = 512, Cc = 256, Tt = 32768;
static constexpr float kLog2e = 1.4426950408889634f;
static constexpr float kLn2 = 0.6931471805599453f;
static constexpr float kInvCount = 1.0f / 131072.0f;  // B * T

typedef short bf16x8 __attribute__((ext_vector_type(8)));
typedef float f32x4 __attribute__((ext_vector_type(4)));

static __device__ __forceinline__ ushort bf16bits(float f) {
  __hip_bfloat16 h = __float2bfloat16(f);
  return *(ushort*)&h;
}

// load 8 consecutive f32 and convert to a bf16x8 MFMA fragment
static __device__ __forceinline__ bf16x8 cvt8(const float* __restrict__ p) {
  float4 a0 = *(const float4*)p;
  float4 a1 = *(const float4*)(p + 4);
  bf16x8 r;
  r[0] = (short)bf16bits(a0.x); r[1] = (short)bf16bits(a0.y);
  r[2] = (short)bf16bits(a0.z); r[3] = (short)bf16bits(a0.w);
  r[4] = (short)bf16bits(a1.x); r[5] = (short)bf16bits(a1.y);
  r[6] = (short)bf16bits(a1.z); r[7] = (short)bf16bits(a1.w);
  return r;
}

// ---------------------------------------------------------------------------
// Fused, 1280 blocks (256 vq via bid%5==0 + 1024 recon of 128 cols each).
// LDS padded to 42.5 KB -> exactly 3 blocks/CU co-resident; retired blocks
// are REFILLED from the queue, keeping the 1:2 vq:recon mix and 12 waves/CU
// alive for the whole kernel (R9's single-round grid lost this after the
// first retirements). Bodies are R9/R10-verbatim; plain loads (no nt).
// ---------------------------------------------------------------------------
__global__ __launch_bounds__(256) void fused_kernel(const float* __restrict__ qp,
                                                    const int* __restrict__ tgt,
                                                    const float* __restrict__ ze,
                                                    const float* __restrict__ emb,
                                                    const float* __restrict__ cw,
                                                    float* __restrict__ part) {
  __shared__ __align__(16) float smem[10624];  // 42496 B -> 3 blocks/CU
  const int tid = threadIdx.x;
  const int bid = blockIdx.x;

  if (bid % 5 == 0) {
    // ------------------------------ VQ role ------------------------------
    ushort* zs = (ushort*)smem;                              // [64][72] bf16
    float* e2s = smem + 2304;                                // [512]
    unsigned long long* red = (unsigned long long*)(smem + 2816);  // [4][64]

    const int vb = bid / 5;               // 0..255
    const int b = vb >> 6;
    const int n0 = (vb & 63) << 6;
    const float* zebase = ze + (size_t)b * Qq * Nn + n0;

    // stage ze f32 -> bf16 transposed tile zs[n][q]
    {
      const int nc = tid & 15;
      const int q0 = tid >> 4;
#pragma unroll
      for (int it = 0; it < 4; ++it) {
        int q = q0 + 16 * it;
        float4 v = *(const float4*)(zebase + (size_t)q * Nn + 4 * nc);
        zs[(4 * nc + 0) * 72 + q] = bf16bits(v.x);
        zs[(4 * nc + 1) * 72 + q] = bf16bits(v.y);
        zs[(4 * nc + 2) * 72 + q] = bf16bits(v.z);
        zs[(4 * nc + 3) * 72 + q] = bf16bits(v.w);
      }
    }
    // ||emb_k||^2 into LDS (emb is 128 KB, L2/L3-resident)
    for (int k = tid; k < Kk; k += 256) {
      const float4* row = (const float4*)(emb + (size_t)k * Qq);
      float a = 0.f;
#pragma unroll
      for (int i = 0; i < 16; ++i) {
        float4 f = row[i];
        a += f.x * f.x + f.y * f.y + f.z * f.z + f.w * f.w;
      }
      e2s[k] = a;
    }
    __syncthreads();

    const int w = tid >> 6, lane = tid & 63;
    const int lc = lane & 15;
    const int lg = lane >> 4;

    bf16x8 bfr[4][2];
#pragma unroll
    for (int ct = 0; ct < 4; ++ct)
#pragma unroll
      for (int ks = 0; ks < 2; ++ks)
        bfr[ct][ks] = *(const bf16x8*)&zs[(ct * 16 + lc) * 72 + ks * 32 + lg * 8];

    unsigned long long pk[4] = {~0ull, ~0ull, ~0ull, ~0ull};
#pragma unroll 2
    for (int mt = 0; mt < 8; ++mt) {
      const int arow = w * 128 + mt * 16 + lc;
      const float* ap = emb + (size_t)arow * Qq;
      f32x4 acc[4] = {{0.f, 0.f, 0.f, 0.f}, {0.f, 0.f, 0.f, 0.f},
                      {0.f, 0.f, 0.f, 0.f}, {0.f, 0.f, 0.f, 0.f}};
#pragma unroll
      for (int ks = 0; ks < 2; ++ks) {
        bf16x8 af = cvt8(ap + ks * 32 + lg * 8);
#pragma unroll
        for (int ct = 0; ct < 4; ++ct)
          acc[ct] = __builtin_amdgcn_mfma_f32_16x16x32_bf16(af, bfr[ct][ks],
                                                            acc[ct], 0, 0, 0);
      }
      const int kbase = w * 128 + mt * 16 + lg * 4;
#pragma unroll
      for (int r = 0; r < 4; ++r) {
        int k = kbase + r;
        float e2v = e2s[k];
#pragma unroll
        for (int ct = 0; ct < 4; ++ct) {
          float sc = e2v - 2.0f * acc[ct][r];
          unsigned u = __float_as_uint(sc);
          u = (u & 0x80000000u) ? ~u : (u | 0x80000000u);
          unsigned long long p = ((unsigned long long)u << 32) | (unsigned)k;
          pk[ct] = (p < pk[ct]) ? p : pk[ct];
        }
      }
    }

#pragma unroll
    for (int ct = 0; ct < 4; ++ct) {
      unsigned long long o = __shfl_xor(pk[ct], 16);
      pk[ct] = (o < pk[ct]) ? o : pk[ct];
      o = __shfl_xor(pk[ct], 32);
      pk[ct] = (o < pk[ct]) ? o : pk[ct];
    }
    if (lane < 16) {
#pragma unroll
      for (int ct = 0; ct < 4; ++ct) red[w * 64 + ct * 16 + lane] = pk[ct];
    }
    __syncthreads();

    if (tid < 64) {   // one lane per column: cross-wave min + exact f32 l2
      unsigned long long mn = red[tid];
#pragma unroll
      for (int ww = 1; ww < 4; ++ww) {
        unsigned long long v = red[ww * 64 + tid];
        mn = (v < mn) ? v : mn;
      }
      int kb = (int)(unsigned)(mn & 0xffffffffull);

      const float* zc = zebase + tid;
      const float* er = emb + (size_t)kb * Qq;
      float l2 = 0.f;
#pragma unroll
      for (int q = 0; q < 64; ++q) {
        float d = zc[(size_t)q * Nn] - er[q];
        l2 += d * d;
      }
      float wacc = 0.f;
#pragma unroll
      for (int i = 0; i < 9; ++i) wacc += cw[i];
      if (n0 + tid == Nn - 1) wacc -= cw[0];   // dropped last timestep tap
      float val = 1.25f * l2 * wacc;           // (1 + GAMMA) * l2 * W_n
#pragma unroll
      for (int off = 32; off > 0; off >>= 1) val += __shfl_down(val, off);
      if (tid == 0) part[1024 + vb] = val;
    }
  } else {
    // ----------------------------- recon role -----------------------------
    // 128 columns/block (R10 body). Wave w: columns col0 + (w>>1)*64 + lane,
    // classes [(w&1)*128, +128). dbuf-16, plain dword loads.
    const int rb = bid - bid / 5 - 1;               // 0..1023
    const int col0 = rb * 128;
    const int b = col0 >> 15;
    const int l = tid & 63, w = tid >> 6;
    const int cl = (w >> 1) * 64 + l;               // column local 0..127
    const int col = col0 + cl;
    const int t = col & (Tt - 1);
    const int h = w & 1;                            // class half
    const int cb0 = h * 128;
    const int tg = tgt[col];
    const float* base = qp + (size_t)b * Cc * Tt + (size_t)cb0 * Tt + t;

    float va[16], vb[16];
    float s0 = 0.f, s1 = 0.f, s2 = 0.f, s3 = 0.f, V = 0.f;

#pragma unroll
    for (int i = 0; i < 16; ++i) va[i] = base[(size_t)i * Tt];

#pragma unroll 1
    for (int c0 = 0; c0 < 128; c0 += 32) {
#pragma unroll
      for (int i = 0; i < 16; ++i) vb[i] = base[(size_t)(c0 + 16 + i) * Tt];
#pragma unroll
      for (int i = 0; i < 16; ++i) {
        float e = __builtin_amdgcn_exp2f(va[i] * kLog2e);
        if ((i & 3) == 0) s0 += e;
        else if ((i & 3) == 1) s1 += e;
        else if ((i & 3) == 2) s2 += e;
        else s3 += e;
        V = (cb0 + c0 + i == tg) ? va[i] : V;
      }
      if (c0 + 32 < 128) {
#pragma unroll
        for (int i = 0; i < 16; ++i) va[i] = base[(size_t)(c0 + 32 + i) * Tt];
      }
#pragma unroll
      for (int i = 0; i < 16; ++i) {
        float e = __builtin_amdgcn_exp2f(vb[i] * kLog2e);
        if ((i & 3) == 0) s0 += e;
        else if ((i & 3) == 1) s1 += e;
        else if ((i & 3) == 2) s2 += e;
        else s3 += e;
        V = (cb0 + c0 + 16 + i == tg) ? vb[i] : V;
      }
    }
    float S = (s0 + s1) + (s2 + s3);

    // merge halves: ssm[h][cl], vvm[h][cl]
    float* ssm = smem;          // [2][128]
    float* vvm = smem + 256;    // [2][128]
    ssm[h * 128 + cl] = S;
    vvm[h * 128 + cl] = V;
    __syncthreads();

    float contrib = 0.f;
    if (tid < 128) {
      float Sm = ssm[tid] + ssm[128 + tid];
      float Vm = vvm[tid] + vvm[128 + tid];
      contrib = kLn2 * __builtin_amdgcn_logf(Sm) - Vm;
#pragma unroll
      for (int off = 32; off > 0; off >>= 1) contrib += __shfl_down(contrib, off);
      if ((tid & 63) == 0) smem[512 + (tid >> 6)] = contrib;
    }
    __syncthreads();
    if (tid == 0) part[rb] = smem[512] + smem[513];
  }
}

// ---------------------------------------------------------------------------
// final: sum 1280 partials (1024 recon + 256 vq), scale, write scalar.
// ---------------------------------------------------------------------------
__global__ __launch_bounds__(256) void final_kernel(const float* __restrict__ part,
                                                    float* __restrict__ out) {
  const int tid = threadIdx.x;
  float s = 0.f;
#pragma unroll
  for (int i = 0; i < 5; ++i) s += part[tid + 256 * i];
#pragma unroll
  for (int off = 32; off > 0; off >>= 1) s += __shfl_down(s, off);
  __shared__ float ws[4];
  if ((tid & 63) == 0) ws[tid >> 6] = s;
  __syncthreads();
  if (tid == 0) out[0] = ((ws[0] + ws[1]) + (ws[2] + ws[3])) * kInvCount;
}

extern "C" void kernel_launch(void* const* d_in, const int* in_sizes, int n_in,
                              void* d_out, int out_size, void* d_ws, size_t ws_size,
                              hipStream_t stream) {
  const float* qp  = (const float*)d_in[0];   // (B, C, T) f32
  const int*   tgt = (const int*)d_in[1];     // (B, T) i32
  const float* ze  = (const float*)d_in[2];   // (B, Q, N) f32
  const float* emb = (const float*)d_in[3];   // (K, Q) f32
  const float* cw  = (const float*)d_in[4];   // (9,) f32
  float* out = (float*)d_out;                 // scalar f32
  float* part = (float*)d_ws;                 // [1280] floats, all written

  fused_kernel<<<dim3(1280), dim3(256), 0, stream>>>(qp, tgt, ze, emb, cw, part);
  final_kernel<<<dim3(1), dim3(256), 0, stream>>>(part, out);
}

// Round 14
// 30.842 us; speedup vs baseline: 1.3195x; 1.3195x over previous
//
#include <hip/hip_runtime.h>
#include <hip/hip_bf16.h>

static constexpr int Qq = 64, Nn = 4096, Kk = 512, Cc = 256, Tt = 32768;
static constexpr float kLog2e = 1.4426950408889634f;
static constexpr float kLn2 = 0.6931471805599453f;
static constexpr float kInvCount = 1.0f / 131072.0f;  // B * T

typedef short bf16x8 __attribute__((ext_vector_type(8)));
typedef float f32x4 __attribute__((ext_vector_type(4)));

static __device__ __forceinline__ ushort bf16bits(float f) {
  __hip_bfloat16 h = __float2bfloat16(f);
  return *(ushort*)&h;
}

// load 8 consecutive f32 and convert to a bf16x8 MFMA fragment
static __device__ __forceinline__ bf16x8 cvt8(const float* __restrict__ p) {
  float4 a0 = *(const float4*)p;
  float4 a1 = *(const float4*)(p + 4);
  bf16x8 r;
  r[0] = (short)bf16bits(a0.x); r[1] = (short)bf16bits(a0.y);
  r[2] = (short)bf16bits(a0.z); r[3] = (short)bf16bits(a0.w);
  r[4] = (short)bf16bits(a1.x); r[5] = (short)bf16bits(a1.y);
  r[6] = (short)bf16bits(a1.z); r[7] = (short)bf16bits(a1.w);
  return r;
}

// ---------------------------------------------------------------------------
// Fused (R9, best measured: 31.0 us): bid%3==0 -> vq role (MFMA argmin +
// exact f32 l2); else recon role (dword loads, register double-buffer 16).
// 768 blocks = 3/CU; vq compute hides under recon's memory stalls.
// ---------------------------------------------------------------------------
__global__ __launch_bounds__(256) void fused_kernel(const float* __restrict__ qp,
                                                    const int* __restrict__ tgt,
                                                    const float* __restrict__ ze,
                                                    const float* __restrict__ emb,
                                                    const float* __restrict__ cw,
                                                    float* __restrict__ part) {
  __shared__ __align__(16) float smem[3456];  // 13824 B
  const int tid = threadIdx.x;
  const int bid = blockIdx.x;

  if (bid % 3 == 0) {
    // ------------------------------ VQ role ------------------------------
    ushort* zs = (ushort*)smem;                              // [64][72] bf16
    float* e2s = smem + 2304;                                // [512]
    unsigned long long* red = (unsigned long long*)(smem + 2816);  // [4][64]

    const int vb = bid / 3;               // 0..255
    const int b = vb >> 6;
    const int n0 = (vb & 63) << 6;
    const float* zebase = ze + (size_t)b * Qq * Nn + n0;

    // stage ze f32 -> bf16 transposed tile zs[n][q]
    {
      const int nc = tid & 15;
      const int q0 = tid >> 4;
#pragma unroll
      for (int it = 0; it < 4; ++it) {
        int q = q0 + 16 * it;
        float4 v = *(const float4*)(zebase + (size_t)q * Nn + 4 * nc);
        zs[(4 * nc + 0) * 72 + q] = bf16bits(v.x);
        zs[(4 * nc + 1) * 72 + q] = bf16bits(v.y);
        zs[(4 * nc + 2) * 72 + q] = bf16bits(v.z);
        zs[(4 * nc + 3) * 72 + q] = bf16bits(v.w);
      }
    }
    // ||emb_k||^2 into LDS (emb is 128 KB, L2/L3-resident)
    for (int k = tid; k < Kk; k += 256) {
      const float4* row = (const float4*)(emb + (size_t)k * Qq);
      float a = 0.f;
#pragma unroll
      for (int i = 0; i < 16; ++i) {
        float4 f = row[i];
        a += f.x * f.x + f.y * f.y + f.z * f.z + f.w * f.w;
      }
      e2s[k] = a;
    }
    __syncthreads();

    const int w = tid >> 6, lane = tid & 63;
    const int lc = lane & 15;
    const int lg = lane >> 4;

    bf16x8 bfr[4][2];
#pragma unroll
    for (int ct = 0; ct < 4; ++ct)
#pragma unroll
      for (int ks = 0; ks < 2; ++ks)
        bfr[ct][ks] = *(const bf16x8*)&zs[(ct * 16 + lc) * 72 + ks * 32 + lg * 8];

    unsigned long long pk[4] = {~0ull, ~0ull, ~0ull, ~0ull};
#pragma unroll 2
    for (int mt = 0; mt < 8; ++mt) {
      const int arow = w * 128 + mt * 16 + lc;
      const float* ap = emb + (size_t)arow * Qq;
      f32x4 acc[4] = {{0.f, 0.f, 0.f, 0.f}, {0.f, 0.f, 0.f, 0.f},
                      {0.f, 0.f, 0.f, 0.f}, {0.f, 0.f, 0.f, 0.f}};
#pragma unroll
      for (int ks = 0; ks < 2; ++ks) {
        bf16x8 af = cvt8(ap + ks * 32 + lg * 8);
#pragma unroll
        for (int ct = 0; ct < 4; ++ct)
          acc[ct] = __builtin_amdgcn_mfma_f32_16x16x32_bf16(af, bfr[ct][ks],
                                                            acc[ct], 0, 0, 0);
      }
      const int kbase = w * 128 + mt * 16 + lg * 4;
#pragma unroll
      for (int r = 0; r < 4; ++r) {
        int k = kbase + r;
        float e2v = e2s[k];
#pragma unroll
        for (int ct = 0; ct < 4; ++ct) {
          float sc = e2v - 2.0f * acc[ct][r];
          unsigned u = __float_as_uint(sc);
          u = (u & 0x80000000u) ? ~u : (u | 0x80000000u);
          unsigned long long p = ((unsigned long long)u << 32) | (unsigned)k;
          pk[ct] = (p < pk[ct]) ? p : pk[ct];
        }
      }
    }

#pragma unroll
    for (int ct = 0; ct < 4; ++ct) {
      unsigned long long o = __shfl_xor(pk[ct], 16);
      pk[ct] = (o < pk[ct]) ? o : pk[ct];
      o = __shfl_xor(pk[ct], 32);
      pk[ct] = (o < pk[ct]) ? o : pk[ct];
    }
    if (lane < 16) {
#pragma unroll
      for (int ct = 0; ct < 4; ++ct) red[w * 64 + ct * 16 + lane] = pk[ct];
    }
    __syncthreads();

    if (tid < 64) {   // one lane per column: cross-wave min + exact f32 l2
      unsigned long long mn = red[tid];
#pragma unroll
      for (int ww = 1; ww < 4; ++ww) {
        unsigned long long v = red[ww * 64 + tid];
        mn = (v < mn) ? v : mn;
      }
      int kb = (int)(unsigned)(mn & 0xffffffffull);

      const float* zc = zebase + tid;
      const float* er = emb + (size_t)kb * Qq;
      float l2 = 0.f;
#pragma unroll
      for (int q = 0; q < 64; ++q) {
        float d = zc[(size_t)q * Nn] - er[q];
        l2 += d * d;
      }
      float wacc = 0.f;
#pragma unroll
      for (int i = 0; i < 9; ++i) wacc += cw[i];
      if (n0 + tid == Nn - 1) wacc -= cw[0];   // dropped last timestep tap
      float val = 1.25f * l2 * wacc;           // (1 + GAMMA) * l2 * W_n
#pragma unroll
      for (int off = 32; off > 0; off >>= 1) val += __shfl_down(val, off);
      if (tid == 0) part[512 + vb] = val;
    }
  } else {
    // ----------------------------- recon role -----------------------------
    // dword loads, register double-buffer 16-deep.
    const int rb = bid - bid / 3 - 1;               // 0..511
    const int col = rb * 256 + tid;                 // 0..131071
    const int b = col >> 15;
    const int t = col & (Tt - 1);
    const int tg = tgt[col];
    const float* base = qp + (size_t)b * Cc * Tt + t;

    float va[16], vb[16];
    float s0 = 0.f, s1 = 0.f, s2 = 0.f, s3 = 0.f, V = 0.f;

#pragma unroll
    for (int i = 0; i < 16; ++i) va[i] = base[(size_t)i * Tt];

#pragma unroll 1
    for (int c0 = 0; c0 < Cc; c0 += 32) {
      // issue window B (classes c0+16 .. c0+32)
#pragma unroll
      for (int i = 0; i < 16; ++i) vb[i] = base[(size_t)(c0 + 16 + i) * Tt];
      // consume window A (classes c0 .. c0+16)
#pragma unroll
      for (int i = 0; i < 16; ++i) {
        float e = __builtin_amdgcn_exp2f(va[i] * kLog2e);
        if ((i & 3) == 0) s0 += e;
        else if ((i & 3) == 1) s1 += e;
        else if ((i & 3) == 2) s2 += e;
        else s3 += e;
        V = (c0 + i == tg) ? va[i] : V;
      }
      // issue window A for next iteration (classes c0+32 .. c0+48)
      if (c0 + 32 < Cc) {
#pragma unroll
        for (int i = 0; i < 16; ++i) va[i] = base[(size_t)(c0 + 32 + i) * Tt];
      }
      // consume window B (classes c0+16 .. c0+32)
#pragma unroll
      for (int i = 0; i < 16; ++i) {
        float e = __builtin_amdgcn_exp2f(vb[i] * kLog2e);
        if ((i & 3) == 0) s0 += e;
        else if ((i & 3) == 1) s1 += e;
        else if ((i & 3) == 2) s2 += e;
        else s3 += e;
        V = (c0 + 16 + i == tg) ? vb[i] : V;
      }
    }
    float S = (s0 + s1) + (s2 + s3);
    float contrib = kLn2 * __builtin_amdgcn_logf(S) - V;

#pragma unroll
    for (int off = 32; off > 0; off >>= 1) contrib += __shfl_down(contrib, off);
    float* wsum = smem + 3328;
    if ((tid & 63) == 0) wsum[tid >> 6] = contrib;
    __syncthreads();
    if (tid == 0) part[rb] = (wsum[0] + wsum[1]) + (wsum[2] + wsum[3]);
  }
}

// ---------------------------------------------------------------------------
// final: sum 768 partials (512 recon + 256 vq), scale, write scalar.
// ---------------------------------------------------------------------------
__global__ __launch_bounds__(256) void final_kernel(const float* __restrict__ part,
                                                    float* __restrict__ out) {
  const int tid = threadIdx.x;
  float s = part[tid] + part[tid + 256] + part[tid + 512];
#pragma unroll
  for (int off = 32; off > 0; off >>= 1) s += __shfl_down(s, off);
  __shared__ float ws[4];
  if ((tid & 63) == 0) ws[tid >> 6] = s;
  __syncthreads();
  if (tid == 0) out[0] = ((ws[0] + ws[1]) + (ws[2] + ws[3])) * kInvCount;
}

extern "C" void kernel_launch(void* const* d_in, const int* in_sizes, int n_in,
                              void* d_out, int out_size, void* d_ws, size_t ws_size,
                              hipStream_t stream) {
  const float* qp  = (const float*)d_in[0];   // (B, C, T) f32
  const int*   tgt = (const int*)d_in[1];     // (B, T) i32
  const float* ze  = (const float*)d_in[2];   // (B, Q, N) f32
  const float* emb = (const float*)d_in[3];   // (K, Q) f32
  const float* cw  = (const float*)d_in[4];   // (9,) f32
  float* out = (float*)d_out;                 // scalar f32
  float* part = (float*)d_ws;                 // [768] floats, all written

  fused_kernel<<<dim3(768), dim3(256), 0, stream>>>(qp, tgt, ze, emb, cw, part);
  final_kernel<<<dim3(1), dim3(256), 0, stream>>>(part, out);
}